// Round 10
// baseline (115.711 us; speedup 1.0000x reference)
//
#include <hip/hip_runtime.h>

#define B_ 4
#define L_ 4096
#define D_ 64
#define N_ 16
#define CHUNK 8
#define NCHUNK (L_ / CHUNK)        // 512
#define TOTCHUNK (B_ * NCHUNK)     // 2048

constexpr float DT_  = 0.1f;
constexpr float EPS_ = 1e-6f;

// ---------------------------------------------------------------------------
// K1: fused projection + local chunk scan + local output + correction matrix.
// 2048 blocks x 64 threads (1 wave) = 8 waves/CU (occupancy doubled vs R7-9;
// K1 is latency-bound, per R9's A/B result). Dot phase reverted to the R7
// half-split shape (fastest measured): o = lane&31 selects output row
// (Bm[n] / Cm[n]), h2 = lane>>5 selects K-half; 1 shfl combine per position.
// Wcor computed from registers (lanes 0-15 keep a[p]) + cm LDS reads.
// ---------------------------------------------------------------------------
__global__ __launch_bounds__(64) void proj_scan_kernel(
    const float* __restrict__ x,  const float* __restrict__ A,
    const float* __restrict__ Wb, const float* __restrict__ bb,
    const float* __restrict__ Wc, const float* __restrict__ bc,
    const float* __restrict__ Wd, const float* __restrict__ bd,
    float* __restrict__ S, float* __restrict__ Cdec,
    float* __restrict__ Wcor, float* __restrict__ out)
{
    const int gc    = blockIdx.x;              // global chunk 0..2047
    const int batch = gc >> 9;                 // gc / NCHUNK
    const int c     = gc & (NCHUNK - 1);
    const int lane  = threadIdx.x;
    const int base0 = batch * L_ + c * CHUNK;

    __shared__ float xs[CHUNK * D_];           // 2 KB
    __shared__ float ag[CHUNK * 32];           // 1 KB  (a[16] | g[16] rows)
    __shared__ float cm[CHUNK * N_];           // 0.5 KB
    __shared__ float wbuf[CHUNK * N_];         // 0.5 KB

    // ---- stage chunk's x (128 float4, 2 per lane) ----
    const float4* xg  = (const float4*)(x + (size_t)base0 * D_);
    float4*       xsv = (float4*)xs;
    xsv[lane]      = xg[lane];
    xsv[64 + lane] = xg[64 + lane];

    // ---- W rows in registers (R7 half-split) ----
    const int o  = lane & 31;                  // 0-15 -> Bm row, 16-31 -> Cm row
    const int h2 = lane >> 5;                  // K-half
    float wreg[32];
    const float* Wrow = (o < 16) ? (Wb + o * D_) : (Wc + (o - 16) * D_);
    const float4* w4p = (const float4*)(Wrow + h2 * 32);
    #pragma unroll
    for (int j = 0; j < 8; j++) {
        float4 w4 = w4p[j];
        wreg[4*j+0] = w4.x; wreg[4*j+1] = w4.y;
        wreg[4*j+2] = w4.z; wreg[4*j+3] = w4.w;
    }
    const float wd   = Wd[lane];
    const float bd0  = bd[0];
    const float An   = A[lane & 15];           // row 0 of (D,N); rows identical
    const float bias = (o < 16) ? bb[o] : bc[o - 16];

    __syncthreads();

    // ---- deltas: 8 butterflies, interleaved so shfl chains pipeline ----
    float r[CHUNK];
    #pragma unroll
    for (int p = 0; p < CHUNK; p++) r[p] = xs[p * D_ + lane] * wd;
    #pragma unroll
    for (int m = 32; m >= 1; m >>= 1) {
        #pragma unroll
        for (int p = 0; p < CHUNK; p++) r[p] += __shfl_xor(r[p], m, 64);
    }
    float delta[CHUNK];
    #pragma unroll
    for (int p = 0; p < CHUNK; p++) {
        float z = r[p] + bd0;
        delta[p] = fmaxf(z, 0.0f) + log1pf(expf(-fabsf(z))) + DT_;
    }

    // ---- Bm/Cm dots (half-split, 1 shfl/position) -> LDS; keep a in regs ---
    float av[CHUNK];
    #pragma unroll
    for (int p = 0; p < CHUNK; p++) {
        float acc = 0.0f;
        const float4* xs4 = (const float4*)(xs + p * D_ + h2 * 32);
        #pragma unroll
        for (int j = 0; j < 8; j++) {
            float4 v = xs4[j];                 // broadcast LDS reads
            acc += v.x * wreg[4*j+0] + v.y * wreg[4*j+1]
                 + v.z * wreg[4*j+2] + v.w * wreg[4*j+3];
        }
        acc += __shfl_xor(acc, 32, 64);        // lanes 0-31 hold full dots
        if (lane < 16) {
            float Bm  = acc + bias;
            float tmp = An * delta[p];
            float a   = expf(tmp);
            float g   = (a - 1.0f) * delta[p] * Bm / (tmp + EPS_);
            ag[p * 32 + lane]      = a;
            ag[p * 32 + 16 + lane] = g;
            av[p] = a;
        } else if (lane < 32) {
            cm[p * 16 + (lane - 16)] = acc + bias;
        }
    }
    __syncthreads();

    // ---- Wcor + Cdec from registers (lanes 0-15; cm read from LDS) ----
    if (lane < 16) {
        float cum = 1.0f;
        #pragma unroll
        for (int p = 0; p < CHUNK; p++) {
            cum *= av[p];
            wbuf[p * N_ + lane] = cm[p * N_ + lane] * cum;
        }
        Cdec[gc * N_ + lane] = cum;
    }

    // ---- local scan (zero init) + local output, LDS-only inner loop ----
    float h[N_];
    #pragma unroll
    for (int i = 0; i < N_; i++) h[i] = 0.0f;
    #pragma unroll
    for (int s = 0; s < CHUNK; s++) {
        float xd = xs[s * D_ + lane];
        const float4* row = (const float4*)(ag + s * 32);
        const float4* crw = (const float4*)(cm + s * 16);
        float acc = 0.0f;
        #pragma unroll
        for (int q = 0; q < 4; q++) {
            float4 a4 = row[q];
            float4 g4 = row[4 + q];
            float4 c4 = crw[q];
            h[4*q+0] = a4.x * h[4*q+0] + g4.x * xd;  acc += c4.x * h[4*q+0];
            h[4*q+1] = a4.y * h[4*q+1] + g4.y * xd;  acc += c4.y * h[4*q+1];
            h[4*q+2] = a4.z * h[4*q+2] + g4.z * xd;  acc += c4.z * h[4*q+2];
            h[4*q+3] = a4.w * h[4*q+3] + g4.w * xd;  acc += c4.w * h[4*q+3];
        }
        out[(size_t)(base0 + s) * D_ + lane] = acc;   // local (zero-init) output
    }
    #pragma unroll
    for (int i = 0; i < N_; i++)
        S[(size_t)(gc * N_ + i) * D_ + lane] = h[i];  // chunk-final local state

    // ---- coalesced blast of wbuf -> global Wcor (128 floats = 32 float4) ---
    __syncthreads();                            // wbuf visible to lanes 16-31
    if (lane < 32)
        ((float4*)(Wcor + (size_t)gc * (CHUNK * N_)))[lane] = ((const float4*)wbuf)[lane];
}

// ---------------------------------------------------------------------------
// K2: cross-chunk exclusive scan. 64 blocks x 64 threads; block=(b,n),
// thread=d; groups of 32 with next-group prefetch (~64 loads in flight).
// Chain is 512 long at CHUNK=8.
// ---------------------------------------------------------------------------
#define G_ 32
__global__ __launch_bounds__(64) void combine(
    float* __restrict__ S, const float* __restrict__ Cdec)
{
    const int b = blockIdx.x >> 4;
    const int n = blockIdx.x & 15;
    const int d = threadIdx.x;
    const int cb = b * NCHUNK;

    float*       baseS = S    + (size_t)(cb * N_ + n) * D_ + d;
    const float* baseA = Cdec + cb * N_ + n;

    float run = 0.0f;
    float sbuf[G_], abuf[G_];
    #pragma unroll
    for (int j = 0; j < G_; j++) {
        sbuf[j] = baseS[(size_t)j * (N_ * D_)];
        abuf[j] = baseA[j * N_];
    }
    for (int cc = 0; cc < NCHUNK; cc += G_) {
        const int cn = (cc + G_ < NCHUNK) ? (cc + G_) : cc;   // last: dummy reload
        float t[G_], u[G_];
        #pragma unroll
        for (int j = 0; j < G_; j++) {
            t[j] = baseS[(size_t)(cn + j) * (N_ * D_)];
            u[j] = baseA[(cn + j) * N_];
        }
        #pragma unroll
        for (int j = 0; j < G_; j++) {
            baseS[(size_t)(cc + j) * (N_ * D_)] = run;        // exclusive prefix
            run = abuf[j] * run + sbuf[j];
        }
        #pragma unroll
        for (int j = 0; j < G_; j++) { sbuf[j] = t[j]; abuf[j] = u[j]; }
    }
}

// ---------------------------------------------------------------------------
// K3: apply correction: out[l,d] += sum_n Wcor_l[n] * init[n,d].
// 2048 blocks x 64 threads (8 waves/CU).
// ---------------------------------------------------------------------------
__global__ __launch_bounds__(64) void apply_kernel(
    const float* __restrict__ Wcor, const float* __restrict__ S,
    float* __restrict__ out)
{
    const int gc    = blockIdx.x;
    const int batch = gc >> 9;
    const int c     = gc & (NCHUNK - 1);
    const int lane  = threadIdx.x;             // = d
    const int base0 = batch * L_ + c * CHUNK;

    __shared__ float wl[CHUNK * N_];           // 0.5 KB

    // stage correction matrix (128 floats = 32 float4)
    if (lane < 32)
        ((float4*)wl)[lane] = ((const float4*)(Wcor + (size_t)gc * (CHUNK * N_)))[lane];

    // chunk-initial state (post-combine S)
    float hi[N_];
    #pragma unroll
    for (int i = 0; i < N_; i++)
        hi[i] = S[(size_t)(gc * N_ + i) * D_ + lane];

    __syncthreads();

    #pragma unroll
    for (int p = 0; p < CHUNK; p++) {
        const float4* crw = (const float4*)(wl + p * N_);
        float acc = 0.0f;
        #pragma unroll
        for (int q = 0; q < 4; q++) {
            float4 w4 = crw[q];
            acc += w4.x * hi[4*q+0] + w4.y * hi[4*q+1]
                 + w4.z * hi[4*q+2] + w4.w * hi[4*q+3];
        }
        const size_t idx = (size_t)(base0 + p) * D_ + lane;
        out[idx] = out[idx] + acc;
    }
}

// ---------------------------------------------------------------------------
extern "C" void kernel_launch(void* const* d_in, const int* in_sizes, int n_in,
                              void* d_out, int out_size, void* d_ws, size_t ws_size,
                              hipStream_t stream)
{
    const float* x  = (const float*)d_in[0];
    const float* A  = (const float*)d_in[1];
    const float* Wb = (const float*)d_in[2];
    const float* bb = (const float*)d_in[3];
    const float* Wc = (const float*)d_in[4];
    const float* bc = (const float*)d_in[5];
    const float* Wd = (const float*)d_in[6];
    const float* bd = (const float*)d_in[7];
    float* out = (float*)d_out;

    // ws carve (floats): S 2097152 (8MB) | Cdec 32768 | Wcor 262144 (1MB)
    float* S    = (float*)d_ws;
    float* Cdec = S    + (size_t)TOTCHUNK * N_ * D_;
    float* Wcor = Cdec + (size_t)TOTCHUNK * N_;

    proj_scan_kernel<<<TOTCHUNK, 64, 0, stream>>>(x, A, Wb, bb, Wc, bc, Wd, bd,
                                                  S, Cdec, Wcor, out);
    combine<<<B_ * N_, 64, 0, stream>>>(S, Cdec);
    apply_kernel<<<TOTCHUNK, 64, 0, stream>>>(Wcor, S, out);
}

// Round 11
// 103.515 us; speedup vs baseline: 1.1178x; 1.1178x over previous
//
#include <hip/hip_runtime.h>

#define B_ 4
#define L_ 4096
#define D_ 64
#define N_ 16
#define CHUNK 16
#define NCHUNK (L_ / CHUNK)        // 256
#define TOTCHUNK (B_ * NCHUNK)     // 1024

constexpr float DT_  = 0.1f;
constexpr float EPS_ = 1e-6f;

// ---------------------------------------------------------------------------
// Best-measured configuration (R7, 103.4 us). 3 dispatches.
// K1: fused projection + local chunk scan + local output + correction matrix.
// 1024 blocks x 64 threads (1 wave), CHUNK=16.
//   - half-split dots: o = lane&31 picks output row (Bm[n]/Cm[n]),
//     h2 = lane>>5 picks K-half; one shfl_xor(32) combine per position.
//   - delta via 16 interleaved 64-lane butterflies (pipelined shfl chains).
//   - coefficients a/g/cm live in LDS only (global coefficient paths
//     measured slower in R8); local scan writes zero-init output to out,
//     chunk-final state to S, chunk decay to Cdec, correction matrix
//     Wcor_l[n] = cm_l[n] * prod_{j<=l} a_j[n] to global.
// ---------------------------------------------------------------------------
__global__ __launch_bounds__(64) void proj_scan_kernel(
    const float* __restrict__ x,  const float* __restrict__ A,
    const float* __restrict__ Wb, const float* __restrict__ bb,
    const float* __restrict__ Wc, const float* __restrict__ bc,
    const float* __restrict__ Wd, const float* __restrict__ bd,
    float* __restrict__ S, float* __restrict__ Cdec,
    float* __restrict__ Wcor, float* __restrict__ out)
{
    const int gc    = blockIdx.x;              // global chunk 0..1023
    const int batch = gc >> 8;
    const int c     = gc & (NCHUNK - 1);
    const int lane  = threadIdx.x;
    const int base0 = batch * L_ + c * CHUNK;

    __shared__ float xs[CHUNK * D_];           // 4 KB
    __shared__ float ag[CHUNK * 32];           // 2 KB
    __shared__ float cm[CHUNK * N_];           // 1 KB
    __shared__ float wbuf[CHUNK * N_];         // 1 KB

    // ---- stage chunk's x ----
    const float4* xg  = (const float4*)(x + (size_t)base0 * D_);
    float4*       xsv = (float4*)xs;
    #pragma unroll
    for (int i = 0; i < 4; i++) xsv[i * 64 + lane] = xg[i * 64 + lane];

    // ---- W rows in registers (overlaps x staging latency) ----
    const int o  = lane & 31;                  // 0-15 -> Bm row, 16-31 -> Cm row
    const int h2 = lane >> 5;                  // K-half
    float wreg[32];
    const float* Wrow = (o < 16) ? (Wb + o * D_) : (Wc + (o - 16) * D_);
    const float4* w4p = (const float4*)(Wrow + h2 * 32);
    #pragma unroll
    for (int j = 0; j < 8; j++) {
        float4 w4 = w4p[j];
        wreg[4*j+0] = w4.x; wreg[4*j+1] = w4.y;
        wreg[4*j+2] = w4.z; wreg[4*j+3] = w4.w;
    }
    const float wd   = Wd[lane];
    const float bd0  = bd[0];
    const float An   = A[lane & 15];           // row 0 of (D,N); rows identical
    const float bias = (o < 16) ? bb[o] : bc[o - 16];

    __syncthreads();

    // ---- deltas: 16 butterflies, interleaved so shfl chains pipeline ----
    float r[CHUNK];
    #pragma unroll
    for (int p = 0; p < CHUNK; p++) r[p] = xs[p * D_ + lane] * wd;
    #pragma unroll
    for (int m = 32; m >= 1; m >>= 1) {
        #pragma unroll
        for (int p = 0; p < CHUNK; p++) r[p] += __shfl_xor(r[p], m, 64);
    }
    float delta[CHUNK];
    #pragma unroll
    for (int p = 0; p < CHUNK; p++) {
        float z = r[p] + bd0;
        delta[p] = fmaxf(z, 0.0f) + log1pf(expf(-fabsf(z))) + DT_;
    }

    // ---- Bm/Cm dots (half-split, 1 shfl/position) -> LDS ----
    #pragma unroll
    for (int p = 0; p < CHUNK; p++) {
        float acc = 0.0f;
        const float4* xs4 = (const float4*)(xs + p * D_ + h2 * 32);
        #pragma unroll
        for (int j = 0; j < 8; j++) {
            float4 v = xs4[j];                 // broadcast LDS reads
            acc += v.x * wreg[4*j+0] + v.y * wreg[4*j+1]
                 + v.z * wreg[4*j+2] + v.w * wreg[4*j+3];
        }
        acc += __shfl_xor(acc, 32, 64);        // lanes 0-31 hold full dots
        if (lane < 16) {
            float Bm  = acc + bias;
            float tmp = An * delta[p];
            float a   = expf(tmp);
            float g   = (a - 1.0f) * delta[p] * Bm / (tmp + EPS_);
            ag[p * 32 + lane]      = a;
            ag[p * 32 + 16 + lane] = g;
        } else if (lane < 32) {
            cm[p * 16 + (lane - 16)] = acc + bias;
        }
    }
    __syncthreads();

    // ---- local scan (zero init) + local output, LDS-only inner loop ----
    float h[N_];
    #pragma unroll
    for (int n = 0; n < N_; n++) h[n] = 0.0f;
    for (int s = 0; s < CHUNK; s++) {
        float xd = xs[s * D_ + lane];
        const float4* row = (const float4*)(ag + s * 32);
        const float4* crw = (const float4*)(cm + s * 16);
        float acc = 0.0f;
        #pragma unroll
        for (int q = 0; q < 4; q++) {
            float4 a4 = row[q];
            float4 g4 = row[4 + q];
            float4 c4 = crw[q];
            h[4*q+0] = a4.x * h[4*q+0] + g4.x * xd;  acc += c4.x * h[4*q+0];
            h[4*q+1] = a4.y * h[4*q+1] + g4.y * xd;  acc += c4.y * h[4*q+1];
            h[4*q+2] = a4.z * h[4*q+2] + g4.z * xd;  acc += c4.z * h[4*q+2];
            h[4*q+3] = a4.w * h[4*q+3] + g4.w * xd;  acc += c4.w * h[4*q+3];
        }
        out[(size_t)(base0 + s) * D_ + lane] = acc;   // local (zero-init) output
    }
    #pragma unroll
    for (int n = 0; n < N_; n++)
        S[(size_t)(gc * N_ + n) * D_ + lane] = h[n];  // chunk-final local state

    // ---- correction matrix + chunk decay (lanes 0..15, lane = n) ----
    if (lane < 16) {
        float cumn = 1.0f;
        for (int s = 0; s < CHUNK; s++) {
            cumn *= ag[s * 32 + lane];                 // prod of a up to s incl.
            wbuf[s * 16 + lane] = cm[s * 16 + lane] * cumn;
        }
        Cdec[gc * N_ + lane] = cumn;
    }
    __syncthreads();
    // coalesced blast of wbuf -> global Wcor (256 floats = 64 float4)
    ((float4*)(Wcor + (size_t)gc * (CHUNK * N_)))[lane] = ((const float4*)wbuf)[lane];
}

// ---------------------------------------------------------------------------
// K2: cross-chunk exclusive scan. 64 blocks x 64 threads; block=(b,n),
// thread=d; groups of 32 with next-group prefetch (~64 loads in flight while
// each ~550 cy group is processed -> serial chain nearly stall-free).
// ---------------------------------------------------------------------------
#define G_ 32
__global__ __launch_bounds__(64) void combine(
    float* __restrict__ S, const float* __restrict__ Cdec)
{
    const int b = blockIdx.x >> 4;
    const int n = blockIdx.x & 15;
    const int d = threadIdx.x;
    const int cb = b * NCHUNK;

    float*       baseS = S    + (size_t)(cb * N_ + n) * D_ + d;
    const float* baseA = Cdec + cb * N_ + n;

    float run = 0.0f;
    float sbuf[G_], abuf[G_];
    #pragma unroll
    for (int j = 0; j < G_; j++) {
        sbuf[j] = baseS[(size_t)j * (N_ * D_)];
        abuf[j] = baseA[j * N_];
    }
    for (int cc = 0; cc < NCHUNK; cc += G_) {
        const int cn = (cc + G_ < NCHUNK) ? (cc + G_) : cc;   // last: dummy reload
        float t[G_], u[G_];
        #pragma unroll
        for (int j = 0; j < G_; j++) {
            t[j] = baseS[(size_t)(cn + j) * (N_ * D_)];
            u[j] = baseA[(cn + j) * N_];
        }
        #pragma unroll
        for (int j = 0; j < G_; j++) {
            baseS[(size_t)(cc + j) * (N_ * D_)] = run;        // exclusive prefix
            run = abuf[j] * run + sbuf[j];
        }
        #pragma unroll
        for (int j = 0; j < G_; j++) { sbuf[j] = t[j]; abuf[j] = u[j]; }
    }
}

// ---------------------------------------------------------------------------
// K3: apply correction: out[l,d] += sum_n Wcor_l[n] * init[n,d].
// 1024 blocks x 64 threads.
// ---------------------------------------------------------------------------
__global__ __launch_bounds__(64) void apply_kernel(
    const float* __restrict__ Wcor, const float* __restrict__ S,
    float* __restrict__ out)
{
    const int gc    = blockIdx.x;
    const int batch = gc >> 8;
    const int c     = gc & (NCHUNK - 1);
    const int lane  = threadIdx.x;             // = d
    const int base0 = batch * L_ + c * CHUNK;

    __shared__ float wl[CHUNK * N_];           // 1 KB

    // stage correction matrix (256 floats = 64 float4, one per lane)
    ((float4*)wl)[lane] = ((const float4*)(Wcor + (size_t)gc * (CHUNK * N_)))[lane];

    // chunk-initial state (post-combine S)
    float hi[N_];
    #pragma unroll
    for (int i = 0; i < N_; i++)
        hi[i] = S[(size_t)(gc * N_ + i) * D_ + lane];

    __syncthreads();

    #pragma unroll
    for (int p = 0; p < CHUNK; p++) {
        const float4* crw = (const float4*)(wl + p * N_);
        float acc = 0.0f;
        #pragma unroll
        for (int q = 0; q < 4; q++) {
            float4 w4 = crw[q];
            acc += w4.x * hi[4*q+0] + w4.y * hi[4*q+1]
                 + w4.z * hi[4*q+2] + w4.w * hi[4*q+3];
        }
        const size_t idx = (size_t)(base0 + p) * D_ + lane;
        out[idx] = out[idx] + acc;
    }
}

// ---------------------------------------------------------------------------
extern "C" void kernel_launch(void* const* d_in, const int* in_sizes, int n_in,
                              void* d_out, int out_size, void* d_ws, size_t ws_size,
                              hipStream_t stream)
{
    const float* x  = (const float*)d_in[0];
    const float* A  = (const float*)d_in[1];
    const float* Wb = (const float*)d_in[2];
    const float* bb = (const float*)d_in[3];
    const float* Wc = (const float*)d_in[4];
    const float* bc = (const float*)d_in[5];
    const float* Wd = (const float*)d_in[6];
    const float* bd = (const float*)d_in[7];
    float* out = (float*)d_out;

    // ws carve (floats): S 1048576 (4MB) | Cdec 16384 | Wcor 262144 (1MB)
    float* S    = (float*)d_ws;
    float* Cdec = S    + (size_t)TOTCHUNK * N_ * D_;
    float* Wcor = Cdec + (size_t)TOTCHUNK * N_;

    proj_scan_kernel<<<TOTCHUNK, 64, 0, stream>>>(x, A, Wb, bb, Wc, bc, Wd, bd,
                                                  S, Cdec, Wcor, out);
    combine<<<B_ * N_, 64, 0, stream>>>(S, Cdec);
    apply_kernel<<<TOTCHUNK, 64, 0, stream>>>(Wcor, S, out);
}